// Round 15
// baseline (233.793 us; speedup 1.0000x reference)
//
#include <hip/hip_runtime.h>

#define DEVI __device__ __forceinline__

typedef __attribute__((ext_vector_type(8))) short bh8;    // 8 x bf16 (as raw shorts)
typedef __attribute__((ext_vector_type(4))) float f32x4;

static constexpr int Bsz  = 4;
static constexpr int Lseq = 2048;
static constexpr int INDIM = 1024;
static constexpr int NH = 16;
static constexpr int HD = 64;
static constexpr int QKVN = 3 * NH * HD;   // 3072
static constexpr int OUTD = 1024;
static constexpr int Mrows = Bsz * Lseq;   // 8192

DEVI unsigned short f2bf(float f) {
    unsigned u = __float_as_uint(f);
    u = u + 0x7fffu + ((u >> 16) & 1u);      // RNE
    return (unsigned short)(u >> 16);
}

// async global->LDS, 16 bytes per lane (HW: wave-uniform LDS base + lane*16)
DEVI void gl2lds16(const unsigned short* g, unsigned short* l) {
    __builtin_amdgcn_global_load_lds(
        (const __attribute__((address_space(1))) void*)g,
        (__attribute__((address_space(3))) void*)l, 16, 0, 0);
}

// ---------------------------------------------------------------- convert X
__global__ __launch_bounds__(256) void convert_f32_bf16(
    const float* __restrict__ in, unsigned short* __restrict__ out, int n8) {
    int i = blockIdx.x * 256 + threadIdx.x;
    if (i >= n8) return;
    const f32x4* p = (const f32x4*)(in + (size_t)i * 8);
    f32x4 a = p[0], b = p[1];
    bh8 o;
    o[0] = (short)f2bf(a[0]); o[1] = (short)f2bf(a[1]);
    o[2] = (short)f2bf(a[2]); o[3] = (short)f2bf(a[3]);
    o[4] = (short)f2bf(b[0]); o[5] = (short)f2bf(b[1]);
    o[6] = (short)f2bf(b[2]); o[7] = (short)f2bf(b[3]);
    *(bh8*)(out + (size_t)i * 8) = o;
}

// ------------------------------------------- transpose W [K][N] -> Wt [N][K] bf16
__global__ __launch_bounds__(256) void transpose_f32_bf16(
    const float* __restrict__ W, unsigned short* __restrict__ Wt, int K, int N) {
    __shared__ unsigned short t[64][65];
    int n0 = blockIdx.x * 64, k0 = blockIdx.y * 64;
    int tid = threadIdx.x;
#pragma unroll
    for (int i = 0; i < 16; ++i) {
        int idx = tid + i * 256;
        int r = idx >> 6, c = idx & 63;
        t[r][c] = f2bf(W[(size_t)(k0 + r) * N + (n0 + c)]);
    }
    __syncthreads();
#pragma unroll
    for (int i = 0; i < 16; ++i) {
        int idx = tid + i * 256;
        int r = idx >> 6, c = idx & 63;
        Wt[(size_t)(n0 + r) * K + (k0 + c)] = t[c][r];
    }
}

// ---------------------------------------------------------------- 256x256 8-phase GEMM
// C = A * Bt^T, A [8192][1024] bf16, Bt [N][1024] bf16. BM=BN=256, BK=64,
// 512 threads = 8 waves (2M x 4N, per-wave 128x64). LDS 128KB linear, double-
// buffered at K-tile granularity. 8 phases/iter over 2 K-tiles; counted
// vmcnt(4) at phases 4/8 only (T3+T4); setprio around MFMA (T5); raw
// s_barrier (NOT __syncthreads -> no vmcnt(0) drain). MODE 0: QKV scatter.
template <int MODE>
__global__ __launch_bounds__(512, 2) void gemm256_8ph(
    const unsigned short* __restrict__ A, const unsigned short* __restrict__ Bt,
    float* __restrict__ Cf, unsigned short* __restrict__ Qg,
    unsigned short* __restrict__ Kg, unsigned short* __restrict__ Vg,
    int ntn, int cpx) {
    __shared__ unsigned short LA[2][16384];   // [buf][256 rows x 64 k] = 32KB each
    __shared__ unsigned short LB[2][16384];
    constexpr int K = 1024;                   // 16 K-tiles of 64, 8 iters
    int tid = threadIdx.x, lane = tid & 63, wave = tid >> 6;
    int bid = blockIdx.x;
    int swz = (bid & 7) * cpx + (bid >> 3);   // bijective XCD swizzle (nwg%8==0)
    int mt = swz / ntn, nt = swz % ntn;
    int m0 = mt * 256, n0 = nt * 256;
    int wr = wave >> 2, wc = wave & 3;        // 2M x 4N wave grid
    int cl = lane & 15, kq = (lane >> 4) * 8;

    int srow = tid >> 3, scol = (tid & 7) * 8;    // staging: 64 rows x 64 k / issue
    const unsigned short* Ag = A + (size_t)(m0 + srow) * K + scol;
    const unsigned short* Bg = Bt + (size_t)(n0 + srow) * K + scol;
    int ldsw = wave * 512;                    // wave-uniform LDS base (elems)

    auto stA = [&](int t, int hf) {           // stage one A half-tile (2 x gl_lds)
        unsigned short* l = &LA[t & 1][hf * 8192] + ldsw;
        const unsigned short* g = Ag + (size_t)(hf * 128) * K + t * 64;
        gl2lds16(g, l);
        gl2lds16(g + (size_t)64 * K, l + 4096);
    };
    auto stB = [&](int t, int hf) {
        unsigned short* l = &LB[t & 1][hf * 8192] + ldsw;
        const unsigned short* g = Bg + (size_t)(hf * 128) * K + t * 64;
        gl2lds16(g, l);
        gl2lds16(g + (size_t)64 * K, l + 4096);
    };

    f32x4 acc[8][4] = {};
    bh8 bfr[4][2];

    // prologue: tile0 full + B(1); retire tile0 (12 issued, keep 4 = B(1))
    stA(0, 0); stA(0, 1); stB(0, 0); stB(0, 1); stB(1, 0); stB(1, 1);
    asm volatile("s_waitcnt vmcnt(4)" ::: "memory");
    __builtin_amdgcn_s_barrier();

#define PHASE(Q, BUF, ISSUE, WAITV)                                            \
    {                                                                          \
        const unsigned short* Ald = &LA[BUF][0];                               \
        const unsigned short* Bld = &LB[BUF][0];                               \
        if (Q == 0) {                                                          \
            _Pragma("unroll")                                                  \
            for (int nf = 0; nf < 4; ++nf)                                     \
                _Pragma("unroll")                                              \
                for (int ks = 0; ks < 2; ++ks)                                 \
                    bfr[nf][ks] = *(const bh8*)(Bld +                          \
                        (wc * 64 + nf * 16 + cl) * 64 + ks * 32 + kq);         \
        }                                                                      \
        bh8 afr[2][2];                                                         \
        _Pragma("unroll")                                                      \
        for (int f = 0; f < 2; ++f)                                            \
            _Pragma("unroll")                                                  \
            for (int ks = 0; ks < 2; ++ks)                                     \
                afr[f][ks] = *(const bh8*)(Ald +                               \
                    (wr * 128 + Q * 32 + f * 16 + cl) * 64 + ks * 32 + kq);    \
        ISSUE;                                                                 \
        __builtin_amdgcn_s_barrier();                                          \
        __builtin_amdgcn_s_setprio(1);                                         \
        _Pragma("unroll")                                                      \
        for (int f = 0; f < 2; ++f)                                            \
            _Pragma("unroll")                                                  \
            for (int nf = 0; nf < 4; ++nf)                                     \
                _Pragma("unroll")                                              \
                for (int ks = 0; ks < 2; ++ks)                                 \
                    acc[Q * 2 + f][nf] = __builtin_amdgcn_mfma_f32_16x16x32_bf16( \
                        afr[f][ks], bfr[nf][ks], acc[Q * 2 + f][nf], 0, 0, 0); \
        __builtin_amdgcn_s_setprio(0);                                         \
        WAITV;                                                                 \
        __builtin_amdgcn_s_barrier();                                          \
    }

    for (int it = 0; it < 8; ++it) {
        int T = 2 * it;
        bool n2 = (T + 2) < 16, n3 = (T + 3) < 16;
        PHASE(0, 0, { stA(T + 1, 0); }, {})
        PHASE(1, 0, { stA(T + 1, 1); }, {})
        PHASE(2, 0, { if (n2) stB(T + 2, 0); }, {})
        PHASE(3, 0, { if (n2) stB(T + 2, 1); },
              { if (n2) asm volatile("s_waitcnt vmcnt(4)" ::: "memory");
                else    asm volatile("s_waitcnt vmcnt(0)" ::: "memory"); })
        PHASE(0, 1, { if (n2) stA(T + 2, 0); }, {})
        PHASE(1, 1, { if (n2) stA(T + 2, 1); }, {})
        PHASE(2, 1, { if (n3) stB(T + 3, 0); }, {})
        PHASE(3, 1, { if (n3) stB(T + 3, 1); },
              { if (n3) asm volatile("s_waitcnt vmcnt(4)" ::: "memory"); })
    }
#undef PHASE

    int rb = (lane >> 4) * 4;
#pragma unroll
    for (int mi = 0; mi < 8; ++mi) {
#pragma unroll
        for (int nj = 0; nj < 4; ++nj) {
#pragma unroll
            for (int r = 0; r < 4; ++r) {
                int gm = m0 + wr * 128 + mi * 16 + rb + r;
                int gn = n0 + wc * 64 + nj * 16 + cl;
                float v = acc[mi][nj][r];
                if (MODE == 0) {
                    int b = gm >> 11, ls = gm & 2047;
                    int sel = gn >> 10, h = (gn >> 6) & 15, d = gn & 63;
                    if (sel == 0)   // Q pre-scaled by 1/sqrt(HD) (exact exp shift)
                        Qg[((size_t)(b * NH + h) * Lseq + ls) * HD + d] = f2bf(v * 0.125f);
                    else if (sel == 1)
                        Kg[((size_t)(b * NH + h) * Lseq + ls) * HD + d] = f2bf(v);
                    else  // V transposed: Vt[bh][d][kv]
                        Vg[((size_t)(b * NH + h) * HD + d) * Lseq + ls] = f2bf(v);
                } else {
                    Cf[(size_t)gm * OUTD + gn] = v;
                }
            }
        }
    }
}

// ---------------------------------------------------------------- GEMM (2-phase 128²)
// kept for out-proj (MODE 1): 512 blocks pack 2 full rounds at 2 blocks/CU.
template <int MODE>
__global__ __launch_bounds__(256) void gemm_bt(
    const unsigned short* __restrict__ A, const unsigned short* __restrict__ Bt,
    float* __restrict__ Cf, unsigned short* __restrict__ Qg,
    unsigned short* __restrict__ Kg, unsigned short* __restrict__ Vg,
    int K, int ntn) {
    __shared__ unsigned short Al[2][128 * 32];
    __shared__ unsigned short Bl[2][128 * 32];
    int tid = threadIdx.x;
    int lane = tid & 63, wave = tid >> 6;
    int mt = blockIdx.x / ntn, nt_ = blockIdx.x % ntn;
    int m0 = mt * 128, n0 = nt_ * 128;
    int wm = (wave >> 1) * 64, wn = (wave & 1) * 64;

    int srow = tid >> 2;
    int skof = (tid & 3) * 8;
    const unsigned short* Ags = A + (size_t)(m0 + srow) * K + skof;
    const unsigned short* Bgs = Bt + (size_t)(n0 + srow) * K + skof;
    int wofs = wave * 512;

    f32x4 acc[4][4] = {};
    int cl = lane & 15, kq = (lane >> 4) * 8;

    int nt = K >> 5;
    gl2lds16(Ags, &Al[0][0] + wofs);
    gl2lds16(Ags + (size_t)64 * K, &Al[0][0] + 2048 + wofs);
    gl2lds16(Bgs, &Bl[0][0] + wofs);
    gl2lds16(Bgs + (size_t)64 * K, &Bl[0][0] + 2048 + wofs);
    __syncthreads();

    int cur = 0;
    for (int t = 0; t < nt; ++t) {
        if (t + 1 < nt) {
            int k1 = (t + 1) * 32;
            gl2lds16(Ags + k1, &Al[cur ^ 1][0] + wofs);
            gl2lds16(Ags + (size_t)64 * K + k1, &Al[cur ^ 1][0] + 2048 + wofs);
            gl2lds16(Bgs + k1, &Bl[cur ^ 1][0] + wofs);
            gl2lds16(Bgs + (size_t)64 * K + k1, &Bl[cur ^ 1][0] + 2048 + wofs);
        }
        bh8 af[4], bf[4];
#pragma unroll
        for (int mi = 0; mi < 4; ++mi)
            af[mi] = *(const bh8*)(&Al[cur][0] + (wm + mi * 16 + cl) * 32 + kq);
#pragma unroll
        for (int nj = 0; nj < 4; ++nj)
            bf[nj] = *(const bh8*)(&Bl[cur][0] + (wn + nj * 16 + cl) * 32 + kq);
#pragma unroll
        for (int mi = 0; mi < 4; ++mi)
#pragma unroll
            for (int nj = 0; nj < 4; ++nj)
                acc[mi][nj] = __builtin_amdgcn_mfma_f32_16x16x32_bf16(
                    af[mi], bf[nj], acc[mi][nj], 0, 0, 0);
        if (t + 1 < nt) __syncthreads();
        cur ^= 1;
    }

    int rb = (lane >> 4) * 4;
#pragma unroll
    for (int mi = 0; mi < 4; ++mi) {
#pragma unroll
        for (int nj = 0; nj < 4; ++nj) {
#pragma unroll
            for (int r = 0; r < 4; ++r) {
                int gm = m0 + wm + mi * 16 + rb + r;
                int gn = n0 + wn + nj * 16 + cl;
                float v = acc[mi][nj][r];
                if (MODE == 0) {
                    int b = gm >> 11, ls = gm & 2047;
                    int sel = gn >> 10, h = (gn >> 6) & 15, d = gn & 63;
                    if (sel == 0)
                        Qg[((size_t)(b * NH + h) * Lseq + ls) * HD + d] = f2bf(v * 0.125f);
                    else if (sel == 1)
                        Kg[((size_t)(b * NH + h) * Lseq + ls) * HD + d] = f2bf(v);
                    else
                        Vg[((size_t)(b * NH + h) * HD + d) * Lseq + ls] = f2bf(v);
                } else {
                    Cf[(size_t)gm * OUTD + gn] = v;
                }
            }
        }
    }
}

// ---------------------------------------------------------------- causal flash attention
// (unchanged — verified R12-R14)
__global__ __launch_bounds__(256) void attn_causal(
    const unsigned short* __restrict__ Qg, const unsigned short* __restrict__ Kg,
    const unsigned short* __restrict__ Vt, unsigned short* __restrict__ Og) {
    __shared__ unsigned short Kl[64 * 64];
    __shared__ unsigned short Vl[64 * 64];
    __shared__ unsigned short Pl[4][16 * 72];
    int tid = threadIdx.x, wave = tid >> 6, lane = tid & 63;
    int bid = blockIdx.x;
    int xcd = bid & 7, slot = bid >> 3;
    int p = slot & 15;
    int bh = ((slot >> 4) << 3) | xcd;
    int b = bh >> 4, h = bh & 15;
    const unsigned short* Qp = Qg + (size_t)bh * Lseq * HD;
    const unsigned short* Kp = Kg + (size_t)bh * Lseq * HD;
    const unsigned short* Vp = Vt + (size_t)bh * HD * Lseq;
    int cl = lane & 15, kq = (lane >> 4) * 8, rb = (lane >> 4) * 4;
    unsigned short* Pw = &Pl[wave][0];

    int srow = tid >> 2;
    int sc0 = (tid & 3) * 16;
    int ssw = (srow & 7) << 3;

    bh8 ones;
#pragma unroll
    for (int i = 0; i < 8; ++i) ones[i] = (short)0x3F80;

    for (int pass = 0; pass < 2; ++pass) {
        int pt = pass ? (31 - p) : p;
        int q0 = pt * 64 + wave * 16;

        bh8 qf0 = *(const bh8*)(Qp + (size_t)(q0 + cl) * HD + kq);
        bh8 qf1 = *(const bh8*)(Qp + (size_t)(q0 + cl) * HD + 32 + kq);

        f32x4 o[4] = {};
        f32x4 osum = {};

        int nblk = pt + 1;
        for (int j = 0; j < nblk; ++j) {
            int kv0 = j * 64;
            const unsigned short* Ks = Kp + (size_t)(kv0 + srow) * HD;
            const unsigned short* Vs = Vp + (size_t)srow * Lseq + kv0;
            bh8 k0 = *(const bh8*)(Ks + sc0);
            bh8 k1 = *(const bh8*)(Ks + sc0 + 8);
            bh8 v0 = *(const bh8*)(Vs + sc0);
            bh8 v1 = *(const bh8*)(Vs + sc0 + 8);
            __syncthreads();
            *(bh8*)(Kl + srow * 64 + (sc0 ^ ssw)) = k0;
            *(bh8*)(Kl + srow * 64 + ((sc0 + 8) ^ ssw)) = k1;
            *(bh8*)(Vl + srow * 64 + (sc0 ^ ssw)) = v0;
            *(bh8*)(Vl + srow * 64 + ((sc0 + 8) ^ ssw)) = v1;
            __syncthreads();
#pragma unroll
            for (int nb = 0; nb < 4; ++nb) {
                int row = nb * 16 + cl, rs = (row & 7) << 3;
                bh8 kf0 = *(const bh8*)(Kl + row * 64 + (kq ^ rs));
                bh8 kf1 = *(const bh8*)(Kl + row * 64 + ((kq + 32) ^ rs));
                f32x4 s = {};
                s = __builtin_amdgcn_mfma_f32_16x16x32_bf16(qf0, kf0, s, 0, 0, 0);
                s = __builtin_amdgcn_mfma_f32_16x16x32_bf16(qf1, kf1, s, 0, 0, 0);
                int col = kv0 + nb * 16 + cl;
#pragma unroll
                for (int r = 0; r < 4; ++r) {
                    float v = s[r];
                    if (col > q0 + rb + r) v = -3e30f;
                    Pw[(rb + r) * 72 + nb * 16 + cl] = f2bf(__expf(v));
                }
            }
            bh8 pa0 = *(const bh8*)(Pw + cl * 72 + kq);
            bh8 pa1 = *(const bh8*)(Pw + cl * 72 + 32 + kq);
#pragma unroll
            for (int db = 0; db < 4; ++db) {
                int dr = db * 16 + cl, ds = (dr & 7) << 3;
                bh8 vf0 = *(const bh8*)(Vl + dr * 64 + (kq ^ ds));
                bh8 vf1 = *(const bh8*)(Vl + dr * 64 + ((kq + 32) ^ ds));
                o[db] = __builtin_amdgcn_mfma_f32_16x16x32_bf16(pa0, vf0, o[db], 0, 0, 0);
                o[db] = __builtin_amdgcn_mfma_f32_16x16x32_bf16(pa1, vf1, o[db], 0, 0, 0);
            }
            osum = __builtin_amdgcn_mfma_f32_16x16x32_bf16(pa0, ones, osum, 0, 0, 0);
            osum = __builtin_amdgcn_mfma_f32_16x16x32_bf16(pa1, ones, osum, 0, 0, 0);
        }
#pragma unroll
        for (int r = 0; r < 4; ++r) {
            float inv = 1.0f / osum[r];
            int row = q0 + rb + r;
            size_t obase = (size_t)(b * Lseq + row) * OUTD + h * HD;
#pragma unroll
            for (int db = 0; db < 4; ++db)
                Og[obase + db * 16 + cl] = f2bf(o[db][r] * inv);
        }
    }
}

// ---------------------------------------------------------------- launch
extern "C" void kernel_launch(void* const* d_in, const int* in_sizes, int n_in,
                              void* d_out, int out_size, void* d_ws, size_t ws_size,
                              hipStream_t stream) {
    (void)in_sizes; (void)n_in; (void)out_size; (void)ws_size;
    const float* X    = (const float*)d_in[0];
    const float* Wqkv = (const float*)d_in[1];
    const float* Wout = (const float*)d_in[2];
    float* out = (float*)d_out;

    char* ws = (char*)d_ws;
    size_t off = 0;
    unsigned short* Xb    = (unsigned short*)(ws + off); off += (size_t)Mrows * INDIM * 2;
    unsigned short* WqkvT = (unsigned short*)(ws + off); off += (size_t)QKVN * INDIM * 2;
    unsigned short* WoutT = (unsigned short*)(ws + off); off += (size_t)OUTD * (NH * HD) * 2;
    unsigned short* Qg    = (unsigned short*)(ws + off); off += (size_t)Mrows * NH * HD * 2;
    unsigned short* Kg    = (unsigned short*)(ws + off); off += (size_t)Mrows * NH * HD * 2;
    unsigned short* Vtg   = (unsigned short*)(ws + off); off += (size_t)Mrows * NH * HD * 2;
    unsigned short* Ob    = (unsigned short*)(ws + off); off += (size_t)Mrows * NH * HD * 2;

    convert_f32_bf16<<<(Mrows * INDIM / 8 + 255) / 256, 256, 0, stream>>>(
        X, Xb, Mrows * INDIM / 8);
    transpose_f32_bf16<<<dim3(QKVN / 64, INDIM / 64), 256, 0, stream>>>(
        Wqkv, WqkvT, INDIM, QKVN);
    transpose_f32_bf16<<<dim3(OUTD / 64, (NH * HD) / 64), 256, 0, stream>>>(
        Wout, WoutT, NH * HD, OUTD);
    // QKV: 256x256 8-phase, grid 32 x 12 = 384 blocks (384 % 8 == 0)
    gemm256_8ph<0><<<(Mrows / 256) * (QKVN / 256), 512, 0, stream>>>(
        Xb, WqkvT, nullptr, Qg, Kg, Vtg, QKVN / 256, (Mrows / 256) * (QKVN / 256) / 8);
    attn_causal<<<Bsz * NH * 16, 256, 0, stream>>>(Qg, Kg, Vtg, Ob);
    gemm_bt<1><<<(Mrows / 128) * (OUTD / 128), 256, 0, stream>>>(
        Ob, WoutT, out, nullptr, nullptr, nullptr, NH * HD, OUTD / 128);
}

// Round 16
// 215.838 us; speedup vs baseline: 1.0832x; 1.0832x over previous
//
#include <hip/hip_runtime.h>

#define DEVI __device__ __forceinline__

typedef __attribute__((ext_vector_type(8))) short bh8;    // 8 x bf16 (as raw shorts)
typedef __attribute__((ext_vector_type(4))) float f32x4;

static constexpr int Bsz  = 4;
static constexpr int Lseq = 2048;
static constexpr int INDIM = 1024;
static constexpr int NH = 16;
static constexpr int HD = 64;
static constexpr int QKVN = 3 * NH * HD;   // 3072
static constexpr int OUTD = 1024;
static constexpr int Mrows = Bsz * Lseq;   // 8192

DEVI unsigned short f2bf(float f) {
    unsigned u = __float_as_uint(f);
    u = u + 0x7fffu + ((u >> 16) & 1u);      // RNE
    return (unsigned short)(u >> 16);
}

// async global->LDS, 16 bytes per lane (HW: wave-uniform LDS base + lane*16)
DEVI void gl2lds16(const unsigned short* g, unsigned short* l) {
    __builtin_amdgcn_global_load_lds(
        (const __attribute__((address_space(1))) void*)g,
        (__attribute__((address_space(3))) void*)l, 16, 0, 0);
}

// ---------------------------------------------------------------- convert X
__global__ __launch_bounds__(256) void convert_f32_bf16(
    const float* __restrict__ in, unsigned short* __restrict__ out, int n8) {
    int i = blockIdx.x * 256 + threadIdx.x;
    if (i >= n8) return;
    const f32x4* p = (const f32x4*)(in + (size_t)i * 8);
    f32x4 a = p[0], b = p[1];
    bh8 o;
    o[0] = (short)f2bf(a[0]); o[1] = (short)f2bf(a[1]);
    o[2] = (short)f2bf(a[2]); o[3] = (short)f2bf(a[3]);
    o[4] = (short)f2bf(b[0]); o[5] = (short)f2bf(b[1]);
    o[6] = (short)f2bf(b[2]); o[7] = (short)f2bf(b[3]);
    *(bh8*)(out + (size_t)i * 8) = o;
}

// ------------------------------------------- transpose W [K][N] -> Wt [N][K] bf16
__global__ __launch_bounds__(256) void transpose_f32_bf16(
    const float* __restrict__ W, unsigned short* __restrict__ Wt, int K, int N) {
    __shared__ unsigned short t[64][65];
    int n0 = blockIdx.x * 64, k0 = blockIdx.y * 64;
    int tid = threadIdx.x;
#pragma unroll
    for (int i = 0; i < 16; ++i) {
        int idx = tid + i * 256;
        int r = idx >> 6, c = idx & 63;
        t[r][c] = f2bf(W[(size_t)(k0 + r) * N + (n0 + c)]);
    }
    __syncthreads();
#pragma unroll
    for (int i = 0; i < 16; ++i) {
        int idx = tid + i * 256;
        int r = idx >> 6, c = idx & 63;
        Wt[(size_t)(n0 + r) * K + (k0 + c)] = t[c][r];
    }
}

// ---------------------------------------------------------------- 256x256 8-phase GEMM
// C = A * Bt^T. BM=BN=256, BK=64, 512 threads = 8 waves (2M x 4N). LDS 128KB,
// double-buffered at K-tile granularity; counted vmcnt(4) at phases 4/8 (T3+T4);
// setprio around MFMA (T5). T2 XOR-swizzle per rule #21: linear DMA dest +
// inverse-swizzled per-lane GLOBAL source (chunk ^= row&7) + swizzled reads
// (col ^= (row&7)<<3) -> 16-way ds_read conflict becomes free 2-way.
template <int MODE>
__global__ __launch_bounds__(512, 2) void gemm256_8ph(
    const unsigned short* __restrict__ A, const unsigned short* __restrict__ Bt,
    float* __restrict__ Cf, unsigned short* __restrict__ Qg,
    unsigned short* __restrict__ Kg, unsigned short* __restrict__ Vg,
    int ntn, int cpx) {
    __shared__ unsigned short LA[2][16384];   // [buf][256 rows x 64 k] = 32KB each
    __shared__ unsigned short LB[2][16384];
    constexpr int K = 1024;                   // 16 K-tiles of 64, 8 iters
    int tid = threadIdx.x, lane = tid & 63, wave = tid >> 6;
    int bid = blockIdx.x;
    int swz = (bid & 7) * cpx + (bid >> 3);   // bijective XCD swizzle (nwg%8==0)
    int mt = swz / ntn, nt = swz % ntn;
    int m0 = mt * 256, n0 = nt * 256;
    int wr = wave >> 2, wc = wave & 3;        // 2M x 4N wave grid
    int cl = lane & 15, kq = (lane >> 4) * 8;

    // staging: lane covers LDS slot (row = wave*8+(lane>>3), chunk = lane&7);
    // source chunk inverse-swizzled so LDS[row][c] = global[row][c ^ (row&7)]
    int srow = tid >> 3;
    int scol = ((tid & 7) ^ (srow & 7)) * 8;
    const unsigned short* Ag = A + (size_t)(m0 + srow) * K + scol;
    const unsigned short* Bg = Bt + (size_t)(n0 + srow) * K + scol;
    int ldsw = wave * 512;                    // wave-uniform LDS base (elems)

    auto stA = [&](int t, int hf) {           // stage one A half-tile (2 x gl_lds)
        unsigned short* l = &LA[t & 1][hf * 8192] + ldsw;
        const unsigned short* g = Ag + (size_t)(hf * 128) * K + t * 64;
        gl2lds16(g, l);
        gl2lds16(g + (size_t)64 * K, l + 4096);
    };
    auto stB = [&](int t, int hf) {
        unsigned short* l = &LB[t & 1][hf * 8192] + ldsw;
        const unsigned short* g = Bg + (size_t)(hf * 128) * K + t * 64;
        gl2lds16(g, l);
        gl2lds16(g + (size_t)64 * K, l + 4096);
    };

    f32x4 acc[8][4] = {};
    bh8 bfr[4][2];

    // prologue: tile0 full + B(1); retire tile0 (12 issued, keep 4 = B(1))
    stA(0, 0); stA(0, 1); stB(0, 0); stB(0, 1); stB(1, 0); stB(1, 1);
    asm volatile("s_waitcnt vmcnt(4)" ::: "memory");
    __builtin_amdgcn_s_barrier();

#define PHASE(Q, BUF, ISSUE, WAITV)                                            \
    {                                                                          \
        const unsigned short* Ald = &LA[BUF][0];                               \
        const unsigned short* Bld = &LB[BUF][0];                               \
        if (Q == 0) {                                                          \
            _Pragma("unroll")                                                  \
            for (int nf = 0; nf < 4; ++nf) {                                   \
                int br = wc * 64 + nf * 16 + cl;                               \
                _Pragma("unroll")                                              \
                for (int ks = 0; ks < 2; ++ks)                                 \
                    bfr[nf][ks] = *(const bh8*)(Bld + br * 64 +                \
                        ((ks * 32 + kq) ^ ((br & 7) << 3)));                   \
            }                                                                  \
        }                                                                      \
        bh8 afr[2][2];                                                         \
        _Pragma("unroll")                                                      \
        for (int f = 0; f < 2; ++f) {                                          \
            int ar = wr * 128 + Q * 32 + f * 16 + cl;                          \
            _Pragma("unroll")                                                  \
            for (int ks = 0; ks < 2; ++ks)                                     \
                afr[f][ks] = *(const bh8*)(Ald + ar * 64 +                     \
                    ((ks * 32 + kq) ^ ((ar & 7) << 3)));                       \
        }                                                                      \
        ISSUE;                                                                 \
        __builtin_amdgcn_s_barrier();                                          \
        __builtin_amdgcn_s_setprio(1);                                         \
        _Pragma("unroll")                                                      \
        for (int f = 0; f < 2; ++f)                                            \
            _Pragma("unroll")                                                  \
            for (int nf = 0; nf < 4; ++nf)                                     \
                _Pragma("unroll")                                              \
                for (int ks = 0; ks < 2; ++ks)                                 \
                    acc[Q * 2 + f][nf] = __builtin_amdgcn_mfma_f32_16x16x32_bf16( \
                        afr[f][ks], bfr[nf][ks], acc[Q * 2 + f][nf], 0, 0, 0); \
        __builtin_amdgcn_s_setprio(0);                                         \
        WAITV;                                                                 \
        __builtin_amdgcn_s_barrier();                                          \
    }

    for (int it = 0; it < 8; ++it) {
        int T = 2 * it;
        bool n2 = (T + 2) < 16, n3 = (T + 3) < 16;
        PHASE(0, 0, { stA(T + 1, 0); }, {})
        PHASE(1, 0, { stA(T + 1, 1); }, {})
        PHASE(2, 0, { if (n2) stB(T + 2, 0); }, {})
        PHASE(3, 0, { if (n2) stB(T + 2, 1); },
              { if (n2) asm volatile("s_waitcnt vmcnt(4)" ::: "memory");
                else    asm volatile("s_waitcnt vmcnt(0)" ::: "memory"); })
        PHASE(0, 1, { if (n2) stA(T + 2, 0); }, {})
        PHASE(1, 1, { if (n2) stA(T + 2, 1); }, {})
        PHASE(2, 1, { if (n3) stB(T + 3, 0); }, {})
        PHASE(3, 1, { if (n3) stB(T + 3, 1); },
              { if (n3) asm volatile("s_waitcnt vmcnt(4)" ::: "memory"); })
    }
#undef PHASE

    int rb = (lane >> 4) * 4;
#pragma unroll
    for (int mi = 0; mi < 8; ++mi) {
#pragma unroll
        for (int nj = 0; nj < 4; ++nj) {
#pragma unroll
            for (int r = 0; r < 4; ++r) {
                int gm = m0 + wr * 128 + mi * 16 + rb + r;
                int gn = n0 + wc * 64 + nj * 16 + cl;
                float v = acc[mi][nj][r];
                if (MODE == 0) {
                    int b = gm >> 11, ls = gm & 2047;
                    int sel = gn >> 10, h = (gn >> 6) & 15, d = gn & 63;
                    if (sel == 0)   // Q pre-scaled by 1/sqrt(HD) (exact exp shift)
                        Qg[((size_t)(b * NH + h) * Lseq + ls) * HD + d] = f2bf(v * 0.125f);
                    else if (sel == 1)
                        Kg[((size_t)(b * NH + h) * Lseq + ls) * HD + d] = f2bf(v);
                    else  // V transposed: Vt[bh][d][kv]
                        Vg[((size_t)(b * NH + h) * HD + d) * Lseq + ls] = f2bf(v);
                } else {
                    Cf[(size_t)gm * OUTD + gn] = v;
                }
            }
        }
    }
}

// ---------------------------------------------------------------- GEMM (2-phase 128²)
// kept for out-proj (MODE 1): 512 blocks pack 2 full rounds at 2 blocks/CU.
template <int MODE>
__global__ __launch_bounds__(256) void gemm_bt(
    const unsigned short* __restrict__ A, const unsigned short* __restrict__ Bt,
    float* __restrict__ Cf, unsigned short* __restrict__ Qg,
    unsigned short* __restrict__ Kg, unsigned short* __restrict__ Vg,
    int K, int ntn) {
    __shared__ unsigned short Al[2][128 * 32];
    __shared__ unsigned short Bl[2][128 * 32];
    int tid = threadIdx.x;
    int lane = tid & 63, wave = tid >> 6;
    int mt = blockIdx.x / ntn, nt_ = blockIdx.x % ntn;
    int m0 = mt * 128, n0 = nt_ * 128;
    int wm = (wave >> 1) * 64, wn = (wave & 1) * 64;

    int srow = tid >> 2;
    int skof = (tid & 3) * 8;
    const unsigned short* Ags = A + (size_t)(m0 + srow) * K + skof;
    const unsigned short* Bgs = Bt + (size_t)(n0 + srow) * K + skof;
    int wofs = wave * 512;

    f32x4 acc[4][4] = {};
    int cl = lane & 15, kq = (lane >> 4) * 8;

    int nt = K >> 5;
    gl2lds16(Ags, &Al[0][0] + wofs);
    gl2lds16(Ags + (size_t)64 * K, &Al[0][0] + 2048 + wofs);
    gl2lds16(Bgs, &Bl[0][0] + wofs);
    gl2lds16(Bgs + (size_t)64 * K, &Bl[0][0] + 2048 + wofs);
    __syncthreads();

    int cur = 0;
    for (int t = 0; t < nt; ++t) {
        if (t + 1 < nt) {
            int k1 = (t + 1) * 32;
            gl2lds16(Ags + k1, &Al[cur ^ 1][0] + wofs);
            gl2lds16(Ags + (size_t)64 * K + k1, &Al[cur ^ 1][0] + 2048 + wofs);
            gl2lds16(Bgs + k1, &Bl[cur ^ 1][0] + wofs);
            gl2lds16(Bgs + (size_t)64 * K + k1, &Bl[cur ^ 1][0] + 2048 + wofs);
        }
        bh8 af[4], bf[4];
#pragma unroll
        for (int mi = 0; mi < 4; ++mi)
            af[mi] = *(const bh8*)(&Al[cur][0] + (wm + mi * 16 + cl) * 32 + kq);
#pragma unroll
        for (int nj = 0; nj < 4; ++nj)
            bf[nj] = *(const bh8*)(&Bl[cur][0] + (wn + nj * 16 + cl) * 32 + kq);
#pragma unroll
        for (int mi = 0; mi < 4; ++mi)
#pragma unroll
            for (int nj = 0; nj < 4; ++nj)
                acc[mi][nj] = __builtin_amdgcn_mfma_f32_16x16x32_bf16(
                    af[mi], bf[nj], acc[mi][nj], 0, 0, 0);
        if (t + 1 < nt) __syncthreads();
        cur ^= 1;
    }

    int rb = (lane >> 4) * 4;
#pragma unroll
    for (int mi = 0; mi < 4; ++mi) {
#pragma unroll
        for (int nj = 0; nj < 4; ++nj) {
#pragma unroll
            for (int r = 0; r < 4; ++r) {
                int gm = m0 + wm + mi * 16 + rb + r;
                int gn = n0 + wn + nj * 16 + cl;
                float v = acc[mi][nj][r];
                if (MODE == 0) {
                    int b = gm >> 11, ls = gm & 2047;
                    int sel = gn >> 10, h = (gn >> 6) & 15, d = gn & 63;
                    if (sel == 0)
                        Qg[((size_t)(b * NH + h) * Lseq + ls) * HD + d] = f2bf(v * 0.125f);
                    else if (sel == 1)
                        Kg[((size_t)(b * NH + h) * Lseq + ls) * HD + d] = f2bf(v);
                    else
                        Vg[((size_t)(b * NH + h) * HD + d) * Lseq + ls] = f2bf(v);
                } else {
                    Cf[(size_t)gm * OUTD + gn] = v;
                }
            }
        }
    }
}

// ---------------------------------------------------------------- causal flash attention
// (unchanged — verified R12-R15)
__global__ __launch_bounds__(256) void attn_causal(
    const unsigned short* __restrict__ Qg, const unsigned short* __restrict__ Kg,
    const unsigned short* __restrict__ Vt, unsigned short* __restrict__ Og) {
    __shared__ unsigned short Kl[64 * 64];
    __shared__ unsigned short Vl[64 * 64];
    __shared__ unsigned short Pl[4][16 * 72];
    int tid = threadIdx.x, wave = tid >> 6, lane = tid & 63;
    int bid = blockIdx.x;
    int xcd = bid & 7, slot = bid >> 3;
    int p = slot & 15;
    int bh = ((slot >> 4) << 3) | xcd;
    int b = bh >> 4, h = bh & 15;
    const unsigned short* Qp = Qg + (size_t)bh * Lseq * HD;
    const unsigned short* Kp = Kg + (size_t)bh * Lseq * HD;
    const unsigned short* Vp = Vt + (size_t)bh * HD * Lseq;
    int cl = lane & 15, kq = (lane >> 4) * 8, rb = (lane >> 4) * 4;
    unsigned short* Pw = &Pl[wave][0];

    int srow = tid >> 2;
    int sc0 = (tid & 3) * 16;
    int ssw = (srow & 7) << 3;

    bh8 ones;
#pragma unroll
    for (int i = 0; i < 8; ++i) ones[i] = (short)0x3F80;

    for (int pass = 0; pass < 2; ++pass) {
        int pt = pass ? (31 - p) : p;
        int q0 = pt * 64 + wave * 16;

        bh8 qf0 = *(const bh8*)(Qp + (size_t)(q0 + cl) * HD + kq);
        bh8 qf1 = *(const bh8*)(Qp + (size_t)(q0 + cl) * HD + 32 + kq);

        f32x4 o[4] = {};
        f32x4 osum = {};

        int nblk = pt + 1;
        for (int j = 0; j < nblk; ++j) {
            int kv0 = j * 64;
            const unsigned short* Ks = Kp + (size_t)(kv0 + srow) * HD;
            const unsigned short* Vs = Vp + (size_t)srow * Lseq + kv0;
            bh8 k0 = *(const bh8*)(Ks + sc0);
            bh8 k1 = *(const bh8*)(Ks + sc0 + 8);
            bh8 v0 = *(const bh8*)(Vs + sc0);
            bh8 v1 = *(const bh8*)(Vs + sc0 + 8);
            __syncthreads();
            *(bh8*)(Kl + srow * 64 + (sc0 ^ ssw)) = k0;
            *(bh8*)(Kl + srow * 64 + ((sc0 + 8) ^ ssw)) = k1;
            *(bh8*)(Vl + srow * 64 + (sc0 ^ ssw)) = v0;
            *(bh8*)(Vl + srow * 64 + ((sc0 + 8) ^ ssw)) = v1;
            __syncthreads();
#pragma unroll
            for (int nb = 0; nb < 4; ++nb) {
                int row = nb * 16 + cl, rs = (row & 7) << 3;
                bh8 kf0 = *(const bh8*)(Kl + row * 64 + (kq ^ rs));
                bh8 kf1 = *(const bh8*)(Kl + row * 64 + ((kq + 32) ^ rs));
                f32x4 s = {};
                s = __builtin_amdgcn_mfma_f32_16x16x32_bf16(qf0, kf0, s, 0, 0, 0);
                s = __builtin_amdgcn_mfma_f32_16x16x32_bf16(qf1, kf1, s, 0, 0, 0);
                int col = kv0 + nb * 16 + cl;
#pragma unroll
                for (int r = 0; r < 4; ++r) {
                    float v = s[r];
                    if (col > q0 + rb + r) v = -3e30f;
                    Pw[(rb + r) * 72 + nb * 16 + cl] = f2bf(__expf(v));
                }
            }
            bh8 pa0 = *(const bh8*)(Pw + cl * 72 + kq);
            bh8 pa1 = *(const bh8*)(Pw + cl * 72 + 32 + kq);
#pragma unroll
            for (int db = 0; db < 4; ++db) {
                int dr = db * 16 + cl, ds = (dr & 7) << 3;
                bh8 vf0 = *(const bh8*)(Vl + dr * 64 + (kq ^ ds));
                bh8 vf1 = *(const bh8*)(Vl + dr * 64 + ((kq + 32) ^ ds));
                o[db] = __builtin_amdgcn_mfma_f32_16x16x32_bf16(pa0, vf0, o[db], 0, 0, 0);
                o[db] = __builtin_amdgcn_mfma_f32_16x16x32_bf16(pa1, vf1, o[db], 0, 0, 0);
            }
            osum = __builtin_amdgcn_mfma_f32_16x16x32_bf16(pa0, ones, osum, 0, 0, 0);
            osum = __builtin_amdgcn_mfma_f32_16x16x32_bf16(pa1, ones, osum, 0, 0, 0);
        }
#pragma unroll
        for (int r = 0; r < 4; ++r) {
            float inv = 1.0f / osum[r];
            int row = q0 + rb + r;
            size_t obase = (size_t)(b * Lseq + row) * OUTD + h * HD;
#pragma unroll
            for (int db = 0; db < 4; ++db)
                Og[obase + db * 16 + cl] = f2bf(o[db][r] * inv);
        }
    }
}

// ---------------------------------------------------------------- launch
extern "C" void kernel_launch(void* const* d_in, const int* in_sizes, int n_in,
                              void* d_out, int out_size, void* d_ws, size_t ws_size,
                              hipStream_t stream) {
    (void)in_sizes; (void)n_in; (void)out_size; (void)ws_size;
    const float* X    = (const float*)d_in[0];
    const float* Wqkv = (const float*)d_in[1];
    const float* Wout = (const float*)d_in[2];
    float* out = (float*)d_out;

    char* ws = (char*)d_ws;
    size_t off = 0;
    unsigned short* Xb    = (unsigned short*)(ws + off); off += (size_t)Mrows * INDIM * 2;
    unsigned short* WqkvT = (unsigned short*)(ws + off); off += (size_t)QKVN * INDIM * 2;
    unsigned short* WoutT = (unsigned short*)(ws + off); off += (size_t)OUTD * (NH * HD) * 2;
    unsigned short* Qg    = (unsigned short*)(ws + off); off += (size_t)Mrows * NH * HD * 2;
    unsigned short* Kg    = (unsigned short*)(ws + off); off += (size_t)Mrows * NH * HD * 2;
    unsigned short* Vtg   = (unsigned short*)(ws + off); off += (size_t)Mrows * NH * HD * 2;
    unsigned short* Ob    = (unsigned short*)(ws + off); off += (size_t)Mrows * NH * HD * 2;

    convert_f32_bf16<<<(Mrows * INDIM / 8 + 255) / 256, 256, 0, stream>>>(
        X, Xb, Mrows * INDIM / 8);
    transpose_f32_bf16<<<dim3(QKVN / 64, INDIM / 64), 256, 0, stream>>>(
        Wqkv, WqkvT, INDIM, QKVN);
    transpose_f32_bf16<<<dim3(OUTD / 64, (NH * HD) / 64), 256, 0, stream>>>(
        Wout, WoutT, NH * HD, OUTD);
    // QKV: 256x256 8-phase + T2 swizzle, grid 32 x 12 = 384 blocks (384 % 8 == 0)
    gemm256_8ph<0><<<(Mrows / 256) * (QKVN / 256), 512, 0, stream>>>(
        Xb, WqkvT, nullptr, Qg, Kg, Vtg, QKVN / 256, (Mrows / 256) * (QKVN / 256) / 8);
    attn_causal<<<Bsz * NH * 16, 256, 0, stream>>>(Qg, Kg, Vtg, Ob);
    gemm_bt<1><<<(Mrows / 128) * (OUTD / 128), 256, 0, stream>>>(
        Ob, WoutT, out, nullptr, nullptr, nullptr, NH * HD, OUTD / 128);
}